// Round 12
// baseline (147.836 us; speedup 1.0000x reference)
//
#include <hip/hip_runtime.h>
#include <hip/hip_bf16.h>
#include <math.h>

#define LEN 128
#define NCELLS 8256
#define TOTAL 349504
#define NCONSTR 8
#define BONUS 1000.0f
#define NT 512

__device__ __host__ constexpr int OFFi(int n){ return (n*(257-n))>>1; }      // row-major index base
__device__ __host__ constexpr int ADIAG(int d){ return (d*(d+1))>>1; }       // diag-major base
constexpr int SOFFc(int l){ int s=0; for(int k=1;k<l;k++) s += (LEN-k)*k; return s; }
constexpr int lgfor(int l){ return l<64?2 : l<96?3 : l<112?4 : l<120?5 : 6; }

// Barrier WITHOUT vmcnt drain (score prefetch stays in flight; T4 discipline).
__device__ __forceinline__ void level_barrier(){
    __builtin_amdgcn_sched_barrier(0);
    asm volatile("s_waitcnt lgkmcnt(0)\n\ts_barrier" ::: "memory");
    __builtin_amdgcn_sched_barrier(0);
}

__device__ __forceinline__ float dpp_xor1_max(float v){
    int r = __builtin_amdgcn_update_dpp(0, __float_as_int(v), 0xB1, 0xF, 0xF, true);
    return fmaxf(v, __int_as_float(r));
}
__device__ __forceinline__ float dpp_xor2_max(float v){
    int r = __builtin_amdgcn_update_dpp(0, __float_as_int(v), 0x4E, 0xF, 0xF, true);
    return fmaxf(v, __int_as_float(r));
}
template<int LG>
__device__ __forceinline__ void redmax2(float& a, float& b){
    #pragma unroll
    for (int mm=(1<<LG)>>1; mm>=4; mm>>=1){
        a=fmaxf(a,__shfl_xor(a,mm));
        b=fmaxf(b,__shfl_xor(b,mm));
    }
    if constexpr (LG>=2){ a=dpp_xor2_max(a); b=dpp_xor2_max(b); }
    if constexpr (LG>=1){ a=dpp_xor1_max(a); b=dpp_xor1_max(b); }
}

__device__ __forceinline__ bool chit(int q, const int4 c0, const int4 c1){
    return (q==c0.x)|(q==c0.y)|(q==c0.z)|(q==c0.w)|
           (q==c1.x)|(q==c1.y)|(q==c1.z)|(q==c1.w);
}

// One level. Right children of (pos,N) = one contiguous run on anti-diagonal
// d=pos+N (addr = ADIAG(d)+N-1-n). Left children carried in registers (lv;
// appended each level at compile-time slot). Bonus folded at write.
template<int LVL, int LG, int LG2>
__device__ __forceinline__ void lstep(const float* __restrict__ g,
    float2* __restrict__ chart, float2 (&lv)[16],
    float (&xc)[16], float (&xn)[16],
    const int4 cc0, const int4 cc1, const int tid)
{
    constexpr int N = LVL, L = LEN - LVL;
    constexpr int T = 1 << LG;
    constexpr int JM = (N + T - 1) / T;
    const int pos = tid >> LG;
    const int sub = tid & (T - 1);

    // ---- prefetch next level's scores (in flight across the barrier) ----
    if constexpr (LG2 >= 0){
        constexpr int T2 = 1 << LG2;
        constexpr int N2 = LVL + 1, L2 = LEN - LVL - 1;
        constexpr int JM2 = (N2 + T2 - 1) / T2;
        constexpr int SO2 = SOFFc(LVL + 1);
        const int pos2 = tid >> LG2, sub2 = tid & (T2 - 1);
        if (pos2 < L2){
            const float* __restrict__ gp = g + SO2 + pos2 * N2 + sub2;
            #pragma unroll
            for (int j = 0; j < JM2; j++)
                if (sub2 + j * T2 < N2) xn[j] = gp[j * T2];
        }
    }

    // ---- contiguous right-child burst from the anti-diagonal ----
    float2 rv[JM];
    {
        const int pc   = (pos < L) ? pos : (L - 1);           // clamp idle lanes
        const int d    = pc + N;
        const int jml  = (N - sub + T - 1) >> LG;             // per-lane valid count
        const int base = ADIAG(d) + (N - 1) - sub;            // >= ADIAG(d) for valid j
        #pragma unroll
        for (int j = 0; j < JM; j++){
            const int a = (j < jml) ? (base - j * T) : 0;     // invalid -> cell(0,0)=0
            rv[j] = chart[a];
        }
    }

    // ---- compute ----
    float bp = -INFINITY, bc = -INFINITY;
    if (pos < L){
        #pragma unroll
        for (int j = 0; j < JM; j++){
            const int n = sub + j * T;
            const float x = (n < N) ? xc[j] : -INFINITY;
            bp = fmaxf(bp, lv[j].x + rv[j].x + x);
            bc = fmaxf(bc, lv[j].y + rv[j].y + x);
        }
    }
    redmax2<LG>(bp, bc);

    // ---- write own cell (diag addr); constraint check uses row-major index ----
    const int qrow = OFFi(N) + pos;
    const float2 cv = make_float2(bp, bc + (chit(qrow, cc0, cc1) ? BONUS : 0.f));
    if (pos < L && sub == 0){
        const int d = pos + N;
        chart[ADIAG(d) + N] = cv;
    }
    // ---- append own value to register left column (slot for n = N) ----
    {
        constexpr int aslot = N >> LG;
        constexpr int asub  = N & (T - 1);
        static_assert(aslot < 16, "slot overflow");
        if (sub == asub) lv[aslot] = cv;
    }
    level_barrier();
}

// Regime transition: re-read the left column (cells (p, n), n < NEWLVL) under
// the new T mapping from the diag-major chart. All source rows are finalized.
template<int NEWLVL, int LGn>
__device__ __forceinline__ void retrans(const float2* __restrict__ chart,
                                        float2 (&lv)[16], const int tid)
{
    constexpr int Tn = 1 << LGn;
    constexpr int JMn = (NEWLVL + Tn - 1) / Tn;
    constexpr int Ln = LEN - NEWLVL;
    const int p = tid >> LGn, s = tid & (Tn - 1);
    const int pc = (p < Ln) ? p : (Ln - 1);
    #pragma unroll
    for (int j = 0; j < JMn; j++){
        const int n  = s + j * Tn;
        const int nn = (n < NEWLVL) ? n : 0;
        lv[j] = chart[ADIAG(pc + nn) + nn];
    }
}

template<int L>
__device__ __forceinline__ void runlv(const float* __restrict__ g,
    float2* __restrict__ chart, float2 (&lv)[16],
    float (&xc)[16], float (&xn)[16],
    const int4 cc0, const int4 cc1, const int tid)
{
    if constexpr (L <= 127){
        constexpr int LG  = lgfor(L);
        constexpr int LG2 = (L < 127) ? lgfor(L + 1) : -1;
        lstep<L, LG, LG2>(g, chart, lv, xc, xn, cc0, cc1, tid);
        if constexpr (L == 63)  retrans<64, 3>(chart, lv, tid);
        if constexpr (L == 95)  retrans<96, 4>(chart, lv, tid);
        if constexpr (L == 111) retrans<112, 5>(chart, lv, tid);
        if constexpr (L == 119) retrans<120, 6>(chart, lv, tid);
        runlv<L + 1>(g, chart, lv, xn, xc, cc0, cc1, tid);
    }
}

__global__ __launch_bounds__(NT)
void cky_fused_kernel(const float* __restrict__ scores,
                      const int* __restrict__ cpos,
                      float* __restrict__ ws)
{
    __shared__ float2 chart[NCELLS];   // DIAG-MAJOR: cell(q,r) at ADIAG(q+r)+r

    const int b   = blockIdx.x;
    const int tid = threadIdx.x;
    const float* __restrict__ g = scores + (size_t)b * TOTAL;

    const int4* __restrict__ cp4 = (const int4*)(cpos + b * NCONSTR);
    const int4 cc0 = cp4[0];
    const int4 cc1 = cp4[1];

    float  xA[16], xB[16];
    float2 lv[16];
    #pragma unroll
    for (int j = 0; j < 16; j++) lv[j] = make_float2(0.f, 0.f);

    // level-1 score prefetch (T=4 mapping)
    {
        const int pos = tid >> 2, sub = tid & 3;
        if (sub == 0 && pos < 127) xA[0] = g[pos];
    }

    // zero row 0 only (cells (q,0) at ADIAG(q)); everything else is
    // written before it is read; invalid-lane reads clamp to cell (0,0).
    if (tid < 128) chart[ADIAG(tid)] = make_float2(0.f, 0.f);
    level_barrier();

    runlv<1>(g, chart, lv, xA, xB, cc0, cc1, tid);

    // ---- per-batch hinge contribution (root (0,127) at ADIAG(127)+127) ----
    if (tid == 0){
        const float2 f = chart[ADIAG(127) + 127];
        const float pred   = f.x;
        const float constr = f.y - BONUS * NCONSTR;
        const float diff   = pred - constr;
        const float mask   = (fabsf(diff) >= 0.001f) ? 1.f : 0.f;
        const float hinge  = fmaxf(1.0f + diff, 0.f) * mask;
        atomicAdd(ws + 0, hinge);
        atomicAdd(ws + 1, mask);
    }
}

__global__ void final_kernel(const float* __restrict__ ws, float* __restrict__ out){
    const float h = ws[0];
    const float m = ws[1];
    out[0] = (m > 0.1f) ? (h / fmaxf(m, 1.f)) : h;
}

extern "C" void kernel_launch(void* const* d_in, const int* in_sizes, int n_in,
                              void* d_out, int out_size, void* d_ws, size_t ws_size,
                              hipStream_t stream) {
    const float* scores = (const float*)d_in[0];
    const int*   cpos   = (const int*)d_in[1];
    float* out = (float*)d_out;
    float* ws  = (float*)d_ws;

    hipMemsetAsync(ws, 0, 2 * sizeof(float), stream);
    cky_fused_kernel<<<dim3(256), dim3(NT), 0, stream>>>(scores, cpos, ws);
    final_kernel<<<dim3(1), dim3(1), 0, stream>>>(ws, out);
}